// Round 9
// baseline (345.340 us; speedup 1.0000x reference)
//
#include <hip/hip_runtime.h>
#include <hip/hip_bf16.h>
#include <stdint.h>

typedef float floatx4 __attribute__((ext_vector_type(4)));
typedef __bf16 bfx8 __attribute__((ext_vector_type(8)));

#define ATT_SCALE 0.08838834764831845f

__device__ __forceinline__ uint16_t f2bf(float f) {
  uint32_t u = __float_as_uint(f);
  return (uint16_t)((u + 0x7fffu + ((u >> 16) & 1u)) >> 16);
}
__device__ __forceinline__ float bf2f(uint32_t bits16) {
  return __uint_as_float(bits16 << 16);
}

typedef __attribute__((address_space(3))) uint32_t lds_u32;
typedef const __attribute__((address_space(1))) uint32_t glob_u32;

// async global->LDS, 16B per lane. LDS dest is wave-uniform base + lane*16.
__device__ __forceinline__ void async_copy16(void* lds, const void* g) {
  uint32_t loff = (uint32_t)(uintptr_t)lds;
  loff = (uint32_t)__builtin_amdgcn_readfirstlane((int)loff);
  lds_u32* lp = reinterpret_cast<lds_u32*>(loff);
  glob_u32* gp = reinterpret_cast<glob_u32*>((uintptr_t)g);
  __builtin_amdgcn_global_load_lds(gp, lp, 16, 0, 0);
}

// ---------------------------------------------------------------------------
// fused fp32 -> bf16 convert for all 5 tensors, 4 elems/thread, one launch.
__global__ void cvt5_kernel(const float* __restrict__ x,  const float* __restrict__ wq,
                            const float* __restrict__ wk, const float* __restrict__ wv,
                            const float* __restrict__ wo,
                            uint16_t* __restrict__ xb,  uint16_t* __restrict__ wqb,
                            uint16_t* __restrict__ wkb, uint16_t* __restrict__ wvb,
                            uint16_t* __restrict__ wob) {
  const int bid = blockIdx.x;
  const float* src; uint16_t* dst; int base;
  if (bid < 8192)       { src = x;  dst = xb;  base = 0; }
  else if (bid < 12288) { src = wq; dst = wqb; base = 8192; }
  else if (bid < 13312) { src = wk; dst = wkb; base = 12288; }
  else if (bid < 14336) { src = wv; dst = wvb; base = 13312; }
  else                  { src = wo; dst = wob; base = 14336; }
  const int i = (((bid - base) << 8) + threadIdx.x) << 2;
  const float4 v = *(const float4*)(src + i);
  uint32_t lo = (uint32_t)f2bf(v.x) | ((uint32_t)f2bf(v.y) << 16);
  uint32_t hi = (uint32_t)f2bf(v.z) | ((uint32_t)f2bf(v.w) << 16);
  *(uint2*)(dst + i) = make_uint2(lo, hi);
}

// ---------------------------------------------------------------------------
// fused in-place RoPE for Q (pre-scaled by ATT_SCALE) and K, one launch.
__global__ void rope2_kernel(uint32_t* __restrict__ qb, uint32_t* __restrict__ kb,
                             const float* __restrict__ freq) {
  const int bid = blockIdx.x;
  uint32_t* buf; int idx, shift; float post;
  if (bid < 16384) { buf = qb; idx = (bid << 8) + threadIdx.x; shift = 10; post = ATT_SCALE; }
  else { buf = kb; idx = ((bid - 16384) << 8) + threadIdx.x; shift = 8; post = 1.0f; }
  const int row = idx >> shift;
  const int cp  = idx & ((1 << shift) - 1);
  const int s = row & 2047;
  const int f = cp & 63;
  const float fr = freq[(s << 6) + f];
  float sn, c;
  sincosf(fr, &sn, &c);
  const uint32_t u = buf[idx];
  const float xr = bf2f(u & 0xffffu);
  const float xi = bf2f(u >> 16);
  const float orr = (xr * c - xi * sn) * post;
  const float oi  = (xr * sn + xi * c) * post;
  buf[idx] = (uint32_t)f2bf(orr) | ((uint32_t)f2bf(oi) << 16);
}

// ---------------------------------------------------------------------------
// 4-wave 128x128 GEMM, BK=32, triple-buffered LDS, counted vmcnt pipeline.
// LDS 48 KB -> 3 blocks/CU. Waves 2(M) x 2(N), per-wave 64x64 (MR=4, NR=4).
// Ring invariants: read frags from buf[t%3]; stage t+2 into buf[(t+2)%3]
// (its t-1 reads finished before the previous barrier); lgkmcnt(0) before
// the barrier; vmcnt(4) retires tile t+1's 4 loads, t+2's stay in flight.
// MODE 0: QKV fused epilogue (Q/K bf16 token-major, V bf16 transposed)
// MODE 1: fp32 out + bias
template <int MODE>
__global__ __launch_bounds__(256, 3) void gemm4(
    const uint16_t* __restrict__ A,
    const uint16_t* __restrict__ Wq, const uint16_t* __restrict__ Wk,
    const uint16_t* __restrict__ Wv,
    const float* __restrict__ bq, const float* __restrict__ bk,
    const float* __restrict__ bv,
    uint16_t* __restrict__ Qo, uint16_t* __restrict__ Ko,
    uint16_t* __restrict__ Vt, float* __restrict__ Fo) {
  constexpr int NT = 64;             // K=2048 / BK=32

  const int tid  = threadIdx.x;
  const int w    = tid >> 6;
  const int lane = tid & 63;
  const int l15  = lane & 15;
  const int l4   = lane >> 4;
  const int wr   = w >> 1;           // 0..1
  const int wc   = w & 1;            // 0..1
  const int bm = blockIdx.x << 7;
  const int n0 = blockIdx.y << 7;

  const uint16_t* Wp;
  int wrow;
  if constexpr (MODE == 0) {
    if (n0 < 2048)      { Wp = Wq; wrow = n0; }
    else if (n0 < 2560) { Wp = Wk; wrow = n0 - 2048; }
    else                { Wp = Wv; wrow = n0 - 2560; }
  } else {
    Wp = Wq; wrow = n0;
  }

  __shared__ uint16_t As[3][128 * 32];
  __shared__ uint16_t Bs[3][128 * 32];

  floatx4 acc[4][4] = {};

  const int srow = lane >> 2;        // 0..15 row within 16-row copy
  const int sg   = lane & 3;         // granule selector

  auto stage = [&](int buf, int t) {
#pragma unroll
    for (int i = 0; i < 2; ++i) {
      const int r0i = (w << 5) + (i << 4);
      const int r = r0i + srow;
      const char* srcA = (const char*)A +
          ((size_t)(bm + r) * 2048 + t * 32) * 2 + ((sg ^ (r & 3)) << 4);
      async_copy16((char*)(As[buf]) + r0i * 64, srcA);
      const char* srcB = (const char*)Wp +
          ((size_t)(wrow + r) * 2048 + t * 32) * 2 + ((sg ^ (r & 3)) << 4);
      async_copy16((char*)(Bs[buf]) + r0i * 64, srcB);
    }
  };

  // prologue: tiles 0,1 into bufs 0,1; wait for tile 0 only (4 loads of t1 fly)
  stage(0, 0);
  stage(1, 1);
  asm volatile("s_waitcnt vmcnt(4)" ::: "memory");
  __builtin_amdgcn_s_barrier();

  int c0 = 0;
  for (int t = 0; t < NT; ++t) {
    const char* AsB = (const char*)(As[c0]);
    const char* BsB = (const char*)(Bs[c0]);

    bfx8 af_[4], bf_[4];
#pragma unroll
    for (int n = 0; n < 4; ++n) {
      const int r = (wc << 6) + (n << 4) + l15;
      bf_[n] = *(const bfx8*)(BsB + r * 64 + ((l4 ^ (r & 3)) << 4));
    }
#pragma unroll
    for (int m = 0; m < 4; ++m) {
      const int r = (wr << 6) + (m << 4) + l15;
      af_[m] = *(const bfx8*)(AsB + r * 64 + ((l4 ^ (r & 3)) << 4));
    }

    int c2 = c0 + 2; if (c2 >= 3) c2 -= 3;
    if (t + 2 < NT) stage(c2, t + 2);

    asm volatile("s_waitcnt lgkmcnt(0)" ::: "memory");
    __builtin_amdgcn_sched_barrier(0);
    __builtin_amdgcn_s_setprio(1);
#pragma unroll
    for (int m = 0; m < 4; ++m)
#pragma unroll
      for (int n = 0; n < 4; ++n)
        acc[m][n] = __builtin_amdgcn_mfma_f32_16x16x32_bf16(af_[m], bf_[n], acc[m][n], 0, 0, 0);
    __builtin_amdgcn_s_setprio(0);

    if (t + 2 < NT)      asm volatile("s_waitcnt vmcnt(4)" ::: "memory");
    else if (t + 1 < NT) asm volatile("s_waitcnt vmcnt(0)" ::: "memory");
    if (t + 1 < NT) __builtin_amdgcn_s_barrier();
    if (++c0 == 3) c0 = 0;
  }

  // epilogue: D row = (lane>>4)*4 + reg, col = lane&15
  const int rb = bm + (wr << 6) + (l4 << 2);
  const int cl = (wc << 6) + l15;
#pragma unroll
  for (int n = 0; n < 4; ++n) {
    const int c = n0 + cl + (n << 4);
#pragma unroll
    for (int m = 0; m < 4; ++m) {
      const int r0 = rb + (m << 4);
      if constexpr (MODE == 1) {
        const float bias = bq[c];
#pragma unroll
        for (int j = 0; j < 4; ++j)
          Fo[(size_t)(r0 + j) * 2048 + c] = acc[m][n][j] + bias;
      } else {
        if (n0 < 2048) {
          const float bias = bq[c];
#pragma unroll
          for (int j = 0; j < 4; ++j)
            Qo[(size_t)(r0 + j) * 2048 + c] = f2bf(acc[m][n][j] + bias);
        } else if (n0 < 2560) {
          const int ck = c - 2048;
          const float bias = bk[ck];
#pragma unroll
          for (int j = 0; j < 4; ++j)
            Ko[(size_t)(r0 + j) * 512 + ck] = f2bf(acc[m][n][j] + bias);
        } else {
          const int cv = c - 2560;
          const float bias = bv[cv];
          const int b = r0 >> 11, s = r0 & 2047;
          const int kv = cv >> 7, dh = cv & 127;
          uint32_t lo = (uint32_t)f2bf(acc[m][n][0] + bias) | ((uint32_t)f2bf(acc[m][n][1] + bias) << 16);
          uint32_t hi = (uint32_t)f2bf(acc[m][n][2] + bias) | ((uint32_t)f2bf(acc[m][n][3] + bias) << 16);
          *(uint2*)(Vt + (size_t)(((b << 2) + kv) * 128 + dh) * 2048 + s) = make_uint2(lo, hi);
        }
      }
    }
  }
}

// ---------------------------------------------------------------------------
// Causal GQA flash attention, 8 waves x 16 q-rows = 128 q-rows per block.
// Balanced pairs: block px handles q-tiles {px, 15-px} (34 KV-iters each).
// K/V double-buffered, prefetch at top, one __syncthreads per KV-tile.
// LDS 80 KB -> 2 blocks/CU (16 waves/CU). Q pre-scaled by ATT_SCALE.
__global__ __launch_bounds__(512, 4) void attn_kernel(
    const uint16_t* __restrict__ Q, const uint16_t* __restrict__ Kb,
    const uint16_t* __restrict__ Vt, uint16_t* __restrict__ O) {
  const int px  = blockIdx.x;          // pair index 0..7
  const int h   = blockIdx.y;
  const int b   = blockIdx.z;
  const int kvh = h >> 2;
  const int tid  = threadIdx.x;
  const int w    = tid >> 6;           // 0..7
  const int lane = tid & 63;
  const int l15 = lane & 15;
  const int l4  = lane >> 4;

  __shared__ uint16_t Ks[2][64 * 128];
  __shared__ uint16_t Vs[2][128 * 64];
  __shared__ uint16_t Ps[8][16 * 64];
  char* PsB = (char*)(Ps[w]);

  const int krow_off = l4;
  const int kscb = l15 << 4;
  const int vrow_off = lane >> 3;
  const int vscb = (lane & 7) << 4;

  auto stageK = [&](int buf, int t) {
    const int kb = t << 6;
#pragma unroll
    for (int i = 0; i < 2; ++i) {
      const int base_r = (w << 3) + (i << 2);
      const int r = base_r + krow_off;
      const int scb = kscb ^ ((r & 7) << 4);
      const char* src = (const char*)Kb + ((size_t)(b * 2048 + kb + r) * 512 + kvh * 128) * 2 + scb;
      async_copy16((char*)(Ks[buf]) + base_r * 256, src);
    }
  };
  auto stageV = [&](int buf, int t) {
    const int kb = t << 6;
#pragma unroll
    for (int i = 0; i < 2; ++i) {
      const int base_r = (w << 4) + (i << 3);
      const int r = base_r + vrow_off;
      const int scb = vscb ^ ((r & 7) << 4);
      const char* src = (const char*)Vt + ((size_t)(((b << 2) + kvh) * 128 + r) * 2048 + kb) * 2 + scb;
      async_copy16((char*)(Vs[buf]) + base_r * 128, src);
    }
  };

  for (int half = 0; half < 2; ++half) {
    const int qt = half ? (15 - px) : px;   // 128-row q-tile index 0..15
    const int qbase = qt << 7;
    const int nt = (qt << 1) + 2;           // KV tiles of 64

    bfx8 qf[4];
    {
      const size_t qrow = (size_t)(b * 2048 + qbase + (w << 4) + l15);
      const char* qp = (const char*)(Q + qrow * 2048 + h * 128 + l4 * 8);
#pragma unroll
      for (int kk = 0; kk < 4; ++kk) qf[kk] = *(const bfx8*)(qp + kk * 64);
    }

    floatx4 oacc[8] = {};
    float mrun[4], lrun[4];
#pragma unroll
    for (int j = 0; j < 4; ++j) { mrun[j] = -1e30f; lrun[j] = 0.0f; }

    stageK(0, 0);
    stageV(0, 0);
    __syncthreads();

    for (int t = 0; t < nt; ++t) {
      const int cur = t & 1;
      if (t + 1 < nt) { stageK(cur ^ 1, t + 1); stageV(cur ^ 1, t + 1); }
      char* KsB = (char*)(Ks[cur]);
      char* VsB = (char*)(Vs[cur]);
      const int kb = t << 6;

      // S = Q K^T (Q pre-scaled)
      floatx4 sc[4] = {};
      __builtin_amdgcn_s_setprio(1);
#pragma unroll
      for (int kk = 0; kk < 4; ++kk) {
        const int cb = (kk << 6) + (l4 << 4);
#pragma unroll
        for (int n = 0; n < 4; ++n) {
          const int r = (n << 4) + l15;
          bfx8 kf = *(const bfx8*)(KsB + r * 256 + (cb ^ ((r & 7) << 4)));
          sc[n] = __builtin_amdgcn_mfma_f32_16x16x32_bf16(qf[kk], kf, sc[n], 0, 0, 0);
        }
      }
      __builtin_amdgcn_s_setprio(0);

      float p[4][4];
      const bool diag = (t >= (qt << 1));   // only last 2 tiles cross the diagonal
#pragma unroll
      for (int n = 0; n < 4; ++n) {
#pragma unroll
        for (int j = 0; j < 4; ++j) {
          float v = sc[n][j];
          if (diag) {
            const int col = kb + (n << 4) + l15;
            const int row = qbase + (w << 4) + (l4 << 2) + j;
            if (col > row) v = -1e30f;
          }
          p[n][j] = v;
        }
      }

      // online softmax: row max via 16-lane shfl reduce; sum kept per-lane partial
#pragma unroll
      for (int j = 0; j < 4; ++j) {
        float pm = fmaxf(fmaxf(p[0][j], p[1][j]), fmaxf(p[2][j], p[3][j]));
#pragma unroll
        for (int off = 8; off > 0; off >>= 1) pm = fmaxf(pm, __shfl_xor(pm, off, 64));
        const float mnew = fmaxf(mrun[j], pm);
        const float sf = __expf(mrun[j] - mnew);
        mrun[j] = mnew;
        float rs = 0.f;
#pragma unroll
        for (int n = 0; n < 4; ++n) {
          p[n][j] = __expf(p[n][j] - mnew);
          rs += p[n][j];
        }
        lrun[j] = lrun[j] * sf + rs;      // per-lane partial; reduced at epilogue
#pragma unroll
        for (int d = 0; d < 8; ++d) oacc[d][j] *= sf;
      }

      // P -> per-wave LDS (wave-private, no barrier)
#pragma unroll
      for (int n = 0; n < 4; ++n) {
        const int cbw = (n << 5) + (l15 << 1);
#pragma unroll
        for (int j = 0; j < 4; ++j) {
          const int r = (l4 << 2) + j;
          *(uint16_t*)(PsB + r * 128 + (cbw ^ ((r & 7) << 4))) = f2bf(p[n][j]);
        }
      }

      // O += P V
      __builtin_amdgcn_s_setprio(1);
#pragma unroll
      for (int kk = 0; kk < 2; ++kk) {
        const int cb = (kk << 6) + (l4 << 4);
        bfx8 pf = *(const bfx8*)(PsB + l15 * 128 + (cb ^ ((l15 & 7) << 4)));
#pragma unroll
        for (int d = 0; d < 8; ++d) {
          const int r = (d << 4) + l15;
          bfx8 vf = *(const bfx8*)(VsB + r * 128 + (cb ^ ((r & 7) << 4)));
          oacc[d] = __builtin_amdgcn_mfma_f32_16x16x32_bf16(pf, vf, oacc[d], 0, 0, 0);
        }
      }
      __builtin_amdgcn_s_setprio(0);

      __syncthreads();
    }

    // epilogue: reduce lrun across 16 lanes, normalize, store bf16
#pragma unroll
    for (int j = 0; j < 4; ++j) {
      float l = lrun[j];
#pragma unroll
      for (int off = 8; off > 0; off >>= 1) l += __shfl_xor(l, off, 64);
      const float inv = 1.0f / l;
      const size_t row = (size_t)(b * 2048 + qbase + (w << 4) + (l4 << 2) + j);
#pragma unroll
      for (int d = 0; d < 8; ++d) {
        const int c = h * 128 + (d << 4) + l15;
        O[row * 2048 + c] = f2bf(oacc[d][j] * inv);
      }
    }
  }
}

// ---------------------------------------------------------------------------
extern "C" void kernel_launch(void* const* d_in, const int* in_sizes, int n_in,
                              void* d_out, int out_size, void* d_ws, size_t ws_size,
                              hipStream_t stream) {
  (void)in_sizes; (void)n_in; (void)out_size; (void)ws_size;
  const float* x         = (const float*)d_in[0];
  const float* rope_freq = (const float*)d_in[1];
  const float* wq_w = (const float*)d_in[3];
  const float* wq_b = (const float*)d_in[4];
  const float* wk_w = (const float*)d_in[5];
  const float* wk_b = (const float*)d_in[6];
  const float* wv_w = (const float*)d_in[7];
  const float* wv_b = (const float*)d_in[8];
  const float* wo_w = (const float*)d_in[9];
  const float* wo_b = (const float*)d_in[10];
  float* out = (float*)d_out;

  char* ws = (char*)d_ws;
  uint16_t* xbf = (uint16_t*)(ws + 0);          // 16 MB : x bf16 (4096,2048)
  uint16_t* wqb = (uint16_t*)(ws + 16777216);   //  8 MB
  uint16_t* wkb = (uint16_t*)(ws + 25165824);   //  2 MB
  uint16_t* wvb = (uint16_t*)(ws + 27262976);   //  2 MB
  uint16_t* wob = (uint16_t*)(ws + 29360128);   //  8 MB
  uint16_t* qbf = (uint16_t*)(ws + 37748736);   // 16 MB : Q (token,2048)
  uint16_t* kbf = (uint16_t*)(ws + 54525952);   //  4 MB : K (token,512)
  uint16_t* vtb = (uint16_t*)(ws + 58720256);   //  4 MB : V^T (b,kv,128,2048)
  uint16_t* att = (uint16_t*)(ws + 62914560);   // 16 MB : attn out (token,2048)

  cvt5_kernel<<<18432, 256, 0, stream>>>(x, wq_w, wk_w, wv_w, wo_w,
                                         xbf, wqb, wkb, wvb, wob);

  gemm4<0><<<dim3(32, 24), 256, 0, stream>>>(
      xbf, wqb, wkb, wvb, wq_b, wk_b, wv_b, qbf, kbf, vtb, nullptr);

  rope2_kernel<<<20480, 256, 0, stream>>>((uint32_t*)qbf, (uint32_t*)kbf, rope_freq);

  attn_kernel<<<dim3(8, 16, 2), 512, 0, stream>>>(qbf, kbf, vtb, att);

  gemm4<1><<<dim3(32, 16), 256, 0, stream>>>(
      att, wob, nullptr, nullptr, wo_b, nullptr, nullptr,
      nullptr, nullptr, nullptr, out);
}